// Round 2
// baseline (14298.053 us; speedup 1.0000x reference)
//
#include <hip/hip_runtime.h>
#include <hip/hip_bf16.h>
#include <cmath>

#define HID 512
#define TSTEPS 784
#define NBLK 256
#define NCLS 10
#define BATCH 256

typedef __bf16 bf16x8 __attribute__((ext_vector_type(8)));
typedef __bf16 bf16x2 __attribute__((ext_vector_type(2)));
typedef float f32x4 __attribute__((ext_vector_type(4)));
typedef float f32x2 __attribute__((ext_vector_type(2)));

__global__ void init_ws(uint4* h0, int n16, unsigned* cnt) {
    int i = blockIdx.x * blockDim.x + threadIdx.x;
    if (i < n16) h0[i] = make_uint4(0u, 0u, 0u, 0u);
    if (i == 0) *cnt = 0u;
}

__device__ __forceinline__ float sigmoid_f(float v) {
    return __fdividef(1.f, 1.f + __expf(-v));
}
__device__ __forceinline__ float tanh_f(float v) {
    float e = __expf(fminf(fmaxf(2.f * v, -30.f), 30.f));   // e^{2v}, clamped
    return __fdividef(e - 1.f, e + 1.f);
}

// Persistent LSTM: 256 blocks = 8 batch-groups(32 rows) x 32 col-slices(16 cols).
// W slice (64 rows x 512) lives in LDS (swizzled) for all 784 steps; c lives in
// registers; h double-buffered in global with a grid barrier per step.
__global__ __launch_bounds__(256, 2)
void lstm_persist(const float* __restrict__ x,      // [256][784]
                  const float* __restrict__ W_hh,   // [2048][512] fp32
                  const float* __restrict__ w_in,   // [2048]
                  const float* __restrict__ b_ih,
                  const float* __restrict__ b_hh,
                  __bf16* __restrict__ h0,          // [256][512] bf16
                  __bf16* __restrict__ h1,
                  float* __restrict__ hf,           // [256][512] fp32 (final h)
                  unsigned* __restrict__ cnt)
{
    __shared__ __align__(16) __bf16 wlds[64 * HID];   // 64 KB, XOR-swizzled
    __shared__ float gl[4][32][17];                   // gate exchange, padded
    __shared__ float xl[32];

    const int tid  = threadIdx.x;
    const int lane = tid & 63;
    const int w    = tid >> 6;           // wave id = gate (i,f,g,o)
    const int bg   = blockIdx.x >> 5;    // batch group (8)
    const int cs   = blockIdx.x & 31;    // col slice (32)
    const int b0   = bg * 32;
    const int j0   = cs * 16;
    const int rlo  = lane & 15;
    const int khi  = (lane >> 4) * 8;

    // ---- stage W slice into LDS once (fp32 -> bf16, swizzled) ----
    {
        int r = tid >> 2;                // local row 0..63
        int q = tid & 3;                 // quarter of K
        int s = r >> 4, jj = r & 15;
        const float* src = W_hh + (s * HID + j0 + jj) * HID + q * 128;
        char* wbp = (char*)wlds;
        unsigned rowb = (unsigned)r * (HID * 2);
        unsigned sw   = (unsigned)(r & 7) << 4;
        #pragma unroll
        for (int cc = 0; cc < 128; cc += 8) {
            float4 va = *(const float4*)(src + cc);
            float4 vb = *(const float4*)(src + cc + 4);
            bf16x8 pk;
            pk[0]=(__bf16)va.x; pk[1]=(__bf16)va.y; pk[2]=(__bf16)va.z; pk[3]=(__bf16)va.w;
            pk[4]=(__bf16)vb.x; pk[5]=(__bf16)vb.y; pk[6]=(__bf16)vb.z; pk[7]=(__bf16)vb.w;
            *(bf16x8*)(wbp + ((rowb + (unsigned)(q * 128 + cc) * 2) ^ sw)) = pk;
        }
    }

    // per-thread cell mapping: row R (0..31), cols c0,c0+1 (of 16)
    const int R  = tid >> 3;
    const int c0 = (tid & 7) * 2;
    float win_r[4][2], bias_r[4][2];
    #pragma unroll
    for (int s = 0; s < 4; ++s)
        #pragma unroll
        for (int ii = 0; ii < 2; ++ii) {
            int idx = s * HID + j0 + c0 + ii;
            win_r[s][ii]  = w_in[idx];
            bias_r[s][ii] = b_ih[idx] + b_hh[idx];
        }
    float creg[2] = {0.f, 0.f};

    __syncthreads();

    // B-fragment LDS base: local row rB = w*16 + rlo
    const int rB = w * 16 + rlo;
    const unsigned rBb = (unsigned)rB * (HID * 2);
    const unsigned swB = (unsigned)(rB & 7) << 4;
    const char* wbp = (const char*)wlds;

    unsigned target = 0;

    for (int t = 0; t < TSTEPS; ++t) {
        const __bf16* hprev = (t & 1) ? h1 : h0;
        __bf16* hnext       = (t & 1) ? h0 : h1;

        // ---- gates tile: 32 rows x 16 cols for gate w ----
        f32x4 acc0 = {0.f,0.f,0.f,0.f}, acc1 = {0.f,0.f,0.f,0.f};
        const __bf16* ap = hprev + (b0 + rlo) * HID + khi;
        #pragma unroll
        for (int ks = 0; ks < 16; ++ks) {
            bf16x8 a0 = *(const bf16x8*)(ap + ks * 32);
            bf16x8 a1 = *(const bf16x8*)(ap + 16 * HID + ks * 32);
            bf16x8 b  = *(const bf16x8*)(wbp + ((rBb + (unsigned)(khi + ks * 32) * 2) ^ swB));
            acc0 = __builtin_amdgcn_mfma_f32_16x16x32_bf16(a0, b, acc0, 0, 0, 0);
            acc1 = __builtin_amdgcn_mfma_f32_16x16x32_bf16(a1, b, acc1, 0, 0, 0);
        }
        #pragma unroll
        for (int rr = 0; rr < 4; ++rr) {
            int rowl = (lane >> 4) * 4 + rr;     // D: col=lane&15, row=(lane>>4)*4+reg
            gl[w][rowl][rlo]      = acc0[rr];
            gl[w][16 + rowl][rlo] = acc1[rr];
        }
        if (tid < 32) xl[tid] = x[(b0 + tid) * TSTEPS + t];
        __syncthreads();

        // ---- cell update (c in registers) ----
        float xv = xl[R];
        float hn2[2];
        #pragma unroll
        for (int ii = 0; ii < 2; ++ii) {
            int cc = c0 + ii;
            float gi = gl[0][R][cc] + xv * win_r[0][ii] + bias_r[0][ii];
            float gf = gl[1][R][cc] + xv * win_r[1][ii] + bias_r[1][ii];
            float gg = gl[2][R][cc] + xv * win_r[2][ii] + bias_r[2][ii];
            float go = gl[3][R][cc] + xv * win_r[3][ii] + bias_r[3][ii];
            float cn = sigmoid_f(gf) * creg[ii] + sigmoid_f(gi) * tanh_f(gg);
            creg[ii] = cn;
            hn2[ii]  = sigmoid_f(go) * tanh_f(cn);
        }
        *(bf16x2*)(hnext + (b0 + R) * HID + j0 + c0) =
            (bf16x2){(__bf16)hn2[0], (__bf16)hn2[1]};
        if (t == TSTEPS - 1)
            *(f32x2*)(hf + (b0 + R) * HID + j0 + c0) = (f32x2){hn2[0], hn2[1]};

        // ---- grid barrier (monotonic counter, agent scope) ----
        target += NBLK;
        __syncthreads();
        if (tid == 0) {
            __hip_atomic_fetch_add(cnt, 1u, __ATOMIC_RELEASE, __HIP_MEMORY_SCOPE_AGENT);
            while (__hip_atomic_load(cnt, __ATOMIC_RELAXED, __HIP_MEMORY_SCOPE_AGENT) < target)
                __builtin_amdgcn_s_sleep(1);
            __builtin_amdgcn_fence(__ATOMIC_ACQUIRE, "agent");
        }
        __syncthreads();
    }
}

// out[b][j] = h_T[b] . W_lin[j] + b_lin[j]
__global__ void head(const float* __restrict__ hfp, const float* __restrict__ Wl,
                     const float* __restrict__ bl_, float* __restrict__ out)
{
    __shared__ float hr[HID];
    int b = blockIdx.x;
    for (int k = threadIdx.x; k < HID; k += blockDim.x) hr[k] = hfp[b * HID + k];
    __syncthreads();
    int j = threadIdx.x;
    if (j < NCLS) {
        float acc = bl_[j];
        for (int k = 0; k < HID; ++k) acc += hr[k] * Wl[j * HID + k];
        out[b * NCLS + j] = acc;
    }
}

extern "C" void kernel_launch(void* const* d_in, const int* in_sizes, int n_in,
                              void* d_out, int out_size, void* d_ws, size_t ws_size,
                              hipStream_t stream) {
    const float* inputs = (const float*)d_in[0];
    const float* W_ih   = (const float*)d_in[1];
    const float* W_hh   = (const float*)d_in[2];
    const float* b_ih   = (const float*)d_in[3];
    const float* b_hh   = (const float*)d_in[4];
    const float* W_lin  = (const float*)d_in[5];
    const float* b_lin  = (const float*)d_in[6];

    // ws: h0 256KB | h1 256KB | hf 512KB | cnt
    const size_t NEEDED = (256u << 10) * 2 + (512u << 10) + 128;
    if (ws_size < NEEDED) return;

    char* ws = (char*)d_ws;
    __bf16* h0 = (__bf16*)ws;
    __bf16* h1 = (__bf16*)(ws + (256u << 10));
    float*  hf = (float*)(ws + (512u << 10));
    unsigned* cnt = (unsigned*)(ws + (1024u << 10));

    // zero h0 (256KB) + counter
    init_ws<<<64, 256, 0, stream>>>((uint4*)h0, (256 << 10) / 16, cnt);

    lstm_persist<<<NBLK, 256, 0, stream>>>(inputs, W_hh, W_ih, b_ih, b_hh,
                                           h0, h1, hf, cnt);

    head<<<BATCH, 64, 0, stream>>>(hf, W_lin, b_lin, (float*)d_out);
}

// Round 4
// 3816.233 us; speedup vs baseline: 3.7466x; 3.7466x over previous
//
#include <hip/hip_runtime.h>
#include <hip/hip_bf16.h>
#include <cmath>

#define HID 512
#define TSTEPS 784
#define BATCH 256
#define NCLS 10
#define NBLK 256
#define GRP 32
#define NGRP 8

typedef __bf16 bf16x8 __attribute__((ext_vector_type(8)));
typedef __bf16 bf16x2 __attribute__((ext_vector_type(2)));
typedef float f32x4 __attribute__((ext_vector_type(4)));
typedef float f32x2 __attribute__((ext_vector_type(2)));
typedef int   i32x4 __attribute__((ext_vector_type(4)));

// row-swizzle helper: rows r and r+16 share a swizzle since (r&7)==((r+16)&7)
#define SWS(r) (((unsigned)(r) & 7u) << 4)

// zero h0+h1 (512KB), zero barrier counters, transpose x -> xT[784][256]
__global__ void init_all(const float* __restrict__ x, float* __restrict__ xT,
                         uint4* __restrict__ hz, unsigned* __restrict__ cnt) {
    int t = blockIdx.x, tid = threadIdx.x;
    xT[t * BATCH + tid] = x[tid * TSTEPS + t];
    int i = t * 256 + tid;
    if (i < (512 << 10) / 16) hz[i] = make_uint4(0u, 0u, 0u, 0u);
    if (i < NGRP * 64) cnt[i] = 0u;
}

__device__ __forceinline__ float sigmoid_f(float v) {
    return __fdividef(1.f, 1.f + __expf(-v));
}
__device__ __forceinline__ float tanh_f(float v) {
    float e = __expf(fminf(fmaxf(2.f * v, -30.f), 30.f));
    return __fdividef(e - 1.f, e + 1.f);
}

// 16B LLC-coherent load (bypass L1+L2)
#define LOADX4_CC(dst, addr) \
    asm volatile("global_load_dwordx4 %0, %1, off sc0 sc1" : "=v"(dst) : "v"(addr) : "memory")

// Persistent LSTM: 256 blocks = 8 batch-groups(32 rows) x 32 col-slices(16 cols).
// Sync is PER GROUP (32 blocks). h exchanged through LLC via sc0sc1 ops; no fences.
__global__ __launch_bounds__(256)
void lstm_persist(const float* __restrict__ xT,     // [784][256]
                  const float* __restrict__ W_hh,   // [2048][512] fp32
                  const float* __restrict__ w_in,   // [2048]
                  const float* __restrict__ b_ih,
                  const float* __restrict__ b_hh,
                  __bf16* __restrict__ h0,          // [256][512] bf16
                  __bf16* __restrict__ h1,
                  float* __restrict__ hf,           // [256][512] fp32
                  unsigned* __restrict__ cnt)
{
    __shared__ __align__(16) __bf16 wlds[64 * HID];   // 64 KB W slice, swizzled
    __shared__ __align__(16) __bf16 hlds[32 * HID];   // 32 KB h slice, swizzled
    __shared__ float gl[4][32][17];
    __shared__ float xl[32];

    const int tid  = threadIdx.x;
    const int lane = tid & 63;
    const int w    = tid >> 6;           // wave id = gate (i,f,g,o)
    const int bg   = blockIdx.x >> 5;    // batch group (8) -> sync group
    const int cs   = blockIdx.x & 31;    // col slice (32)
    const int b0   = bg * 32;
    const int j0   = cs * 16;
    const int rlo  = lane & 15;
    const int khi  = (lane >> 4) * 8;    // elements

    unsigned* mycnt = cnt + bg * 64;     // 256B-separated per-group counter

    // ---- stage W slice into LDS once (fp32 -> bf16, swizzled) ----
    {
        int r = tid >> 2;                // local row 0..63
        int q = tid & 3;
        int s = r >> 4, jj = r & 15;
        const float* src = W_hh + (size_t)(s * HID + j0 + jj) * HID + q * 128;
        char* wbp = (char*)wlds;
        unsigned rowb = (unsigned)r * (HID * 2);
        unsigned sw   = (unsigned)(r & 7) << 4;
        #pragma unroll
        for (int cc = 0; cc < 128; cc += 8) {
            float4 va = *(const float4*)(src + cc);
            float4 vb = *(const float4*)(src + cc + 4);
            bf16x8 pk;
            pk[0]=(__bf16)va.x; pk[1]=(__bf16)va.y; pk[2]=(__bf16)va.z; pk[3]=(__bf16)va.w;
            pk[4]=(__bf16)vb.x; pk[5]=(__bf16)vb.y; pk[6]=(__bf16)vb.z; pk[7]=(__bf16)vb.w;
            *(bf16x8*)(wbp + ((rowb + (unsigned)(q * 128 + cc) * 2) ^ sw)) = pk;
        }
    }

    // per-thread cell mapping: row R (0..31), cols c0,c0+1 (of 16)
    const int R  = tid >> 3;
    const int c0 = (tid & 7) * 2;
    float win_r[4][2], bias_r[4][2];
    #pragma unroll
    for (int s = 0; s < 4; ++s)
        #pragma unroll
        for (int ii = 0; ii < 2; ++ii) {
            int idx = s * HID + j0 + c0 + ii;
            win_r[s][ii]  = w_in[idx];
            bias_r[s][ii] = b_ih[idx] + b_hh[idx];
        }
    float creg[2] = {0.f, 0.f};

    // staging mapping: row rS (0..31), segment seg (0..7) of 64 cols
    const int rS  = tid & 31;
    const int seg = tid >> 5;
    const unsigned rowbS = (unsigned)rS * (HID * 2);
    const unsigned swS   = SWS(rS);

    // B-fragment base: local W row rB = w*16 + rlo
    const unsigned rBb = (unsigned)(w * 16 + rlo) * (HID * 2);
    const unsigned swB = SWS(rlo);
    const char* wbp = (const char*)wlds;
    const char* hbp = (const char*)hlds;
    char* hwp = (char*)hlds;

    __syncthreads();

    unsigned target = 0;

    for (int t = 0; t < TSTEPS; ++t) {
        const __bf16* hprev = (t & 1) ? h1 : h0;
        __bf16* hnext       = (t & 1) ? h0 : h1;

        // ---- stage h slice (32 rows x 512) into LDS via LLC-coherent loads ----
        {
            const __bf16* gsrc = hprev + (size_t)(b0 + rS) * HID + seg * 64;
            i32x4 t0, t1, t2, t3, t4, t5, t6, t7;
            LOADX4_CC(t0, gsrc);      LOADX4_CC(t1, gsrc + 8);
            LOADX4_CC(t2, gsrc + 16); LOADX4_CC(t3, gsrc + 24);
            LOADX4_CC(t4, gsrc + 32); LOADX4_CC(t5, gsrc + 40);
            LOADX4_CC(t6, gsrc + 48); LOADX4_CC(t7, gsrc + 56);
            asm volatile("s_waitcnt vmcnt(0)" ::: "memory");
            __builtin_amdgcn_sched_barrier(0);
            unsigned base = rowbS + (unsigned)seg * 128u;
            *(i32x4*)(hwp + ((base +   0u) ^ swS)) = t0;
            *(i32x4*)(hwp + ((base +  16u) ^ swS)) = t1;
            *(i32x4*)(hwp + ((base +  32u) ^ swS)) = t2;
            *(i32x4*)(hwp + ((base +  48u) ^ swS)) = t3;
            *(i32x4*)(hwp + ((base +  64u) ^ swS)) = t4;
            *(i32x4*)(hwp + ((base +  80u) ^ swS)) = t5;
            *(i32x4*)(hwp + ((base +  96u) ^ swS)) = t6;
            *(i32x4*)(hwp + ((base + 112u) ^ swS)) = t7;
        }
        if (tid < 32) xl[tid] = xT[t * BATCH + b0 + tid];
        __syncthreads();   // hlds + xl ready

        // ---- gates tile: 32 rows x 16 cols for gate w ----
        f32x4 acc0 = {0.f,0.f,0.f,0.f}, acc1 = {0.f,0.f,0.f,0.f};
        #pragma unroll
        for (int ks = 0; ks < 16; ++ks) {
            unsigned colb = (unsigned)(khi * 2 + ks * 64);
            bf16x8 a0 = *(const bf16x8*)(hbp + (((unsigned)rlo * 1024u + colb) ^ SWS(rlo)));
            bf16x8 a1 = *(const bf16x8*)(hbp + (((unsigned)(16 + rlo) * 1024u + colb) ^ SWS(rlo)));
            bf16x8 b  = *(const bf16x8*)(wbp + ((rBb + colb) ^ swB));
            acc0 = __builtin_amdgcn_mfma_f32_16x16x32_bf16(a0, b, acc0, 0, 0, 0);
            acc1 = __builtin_amdgcn_mfma_f32_16x16x32_bf16(a1, b, acc1, 0, 0, 0);
        }
        #pragma unroll
        for (int rr = 0; rr < 4; ++rr) {
            int rowl = (lane >> 4) * 4 + rr;
            gl[w][rowl][rlo]      = acc0[rr];
            gl[w][16 + rowl][rlo] = acc1[rr];
        }
        __syncthreads();   // gl ready

        // ---- cell update (c in registers) ----
        {
            float xv = xl[R];
            float hn2[2];
            #pragma unroll
            for (int ii = 0; ii < 2; ++ii) {
                int ccx = c0 + ii;
                float gi = gl[0][R][ccx] + xv * win_r[0][ii] + bias_r[0][ii];
                float gf = gl[1][R][ccx] + xv * win_r[1][ii] + bias_r[1][ii];
                float gg = gl[2][R][ccx] + xv * win_r[2][ii] + bias_r[2][ii];
                float go = gl[3][R][ccx] + xv * win_r[3][ii] + bias_r[3][ii];
                float cn = sigmoid_f(gf) * creg[ii] + sigmoid_f(gi) * tanh_f(gg);
                creg[ii] = cn;
                hn2[ii]  = sigmoid_f(go) * tanh_f(cn);
            }
            // write-through to LLC
            union { bf16x2 v; int i; } u;
            u.v = (bf16x2){(__bf16)hn2[0], (__bf16)hn2[1]};
            __bf16* dst = hnext + (size_t)(b0 + R) * HID + j0 + c0;
            asm volatile("global_store_dword %0, %1, off sc0 sc1"
                         :: "v"(dst), "v"(u.i) : "memory");
            if (t == TSTEPS - 1)
                *(f32x2*)(hf + (size_t)(b0 + R) * HID + j0 + c0) = (f32x2){hn2[0], hn2[1]};
        }

        if (t == TSTEPS - 1) break;

        // ---- per-group barrier (32 blocks), monotonic counter ----
        asm volatile("s_waitcnt vmcnt(0)" ::: "memory");
        __syncthreads();               // all threads' h stores are at LLC
        target += GRP;
        if (tid == 0) {
            __hip_atomic_fetch_add(mycnt, 1u, __ATOMIC_RELAXED, __HIP_MEMORY_SCOPE_AGENT);
            while (__hip_atomic_load(mycnt, __ATOMIC_RELAXED, __HIP_MEMORY_SCOPE_AGENT) < target)
                __builtin_amdgcn_s_sleep(2);
        }
        __syncthreads();               // group advanced; safe to read hprev
    }
}

// out[b][j] = h_T[b] . W_lin[j] + b_lin[j]
__global__ void head(const float* __restrict__ hfp, const float* __restrict__ Wl,
                     const float* __restrict__ bl_, float* __restrict__ out)
{
    __shared__ float hr[HID];
    int b = blockIdx.x;
    for (int k = threadIdx.x; k < HID; k += blockDim.x) hr[k] = hfp[b * HID + k];
    __syncthreads();
    int j = threadIdx.x;
    if (j < NCLS) {
        float acc = bl_[j];
        for (int k = 0; k < HID; ++k) acc += hr[k] * Wl[j * HID + k];
        out[b * NCLS + j] = acc;
    }
}

extern "C" void kernel_launch(void* const* d_in, const int* in_sizes, int n_in,
                              void* d_out, int out_size, void* d_ws, size_t ws_size,
                              hipStream_t stream) {
    const float* inputs = (const float*)d_in[0];
    const float* W_ih   = (const float*)d_in[1];
    const float* W_hh   = (const float*)d_in[2];
    const float* b_ih   = (const float*)d_in[3];
    const float* b_hh   = (const float*)d_in[4];
    const float* W_lin  = (const float*)d_in[5];
    const float* b_lin  = (const float*)d_in[6];

    // ws: h0 256K | h1 256K | hf 512K | xT 784K+ | cnt 2K
    const size_t OFS_H1  = 256u << 10;
    const size_t OFS_HF  = 512u << 10;
    const size_t OFS_XT  = 1024u << 10;
    const size_t OFS_CNT = OFS_XT + (size_t)TSTEPS * BATCH * 4;   // 128B-aligned
    const size_t NEEDED  = OFS_CNT + NGRP * 64 * 4;
    if (ws_size < NEEDED) return;

    char* ws = (char*)d_ws;
    __bf16* h0 = (__bf16*)ws;
    __bf16* h1 = (__bf16*)(ws + OFS_H1);
    float*  hf = (float*)(ws + OFS_HF);
    float*  xT = (float*)(ws + OFS_XT);
    unsigned* cnt = (unsigned*)(ws + OFS_CNT);

    init_all<<<TSTEPS, BATCH, 0, stream>>>(inputs, xT, (uint4*)h0, cnt);

    lstm_persist<<<NBLK, 256, 0, stream>>>(xT, W_hh, W_ih, b_ih, b_hh,
                                           h0, h1, hf, cnt);

    head<<<BATCH, 64, 0, stream>>>(hf, W_lin, b_lin, (float*)d_out);
}